// Round 6
// baseline (436.672 us; speedup 1.0000x reference)
//
#include <hip/hip_runtime.h>
#include <math.h>

#define E_TOTAL 32768
#define NUM_NODES 4096
#define SCALE 0.70710678118654752f

typedef __attribute__((ext_vector_type(8))) short bfrag;
typedef __attribute__((ext_vector_type(16))) float facc;

__device__ inline unsigned short f2bf(float f) {
  unsigned int u = __float_as_uint(f);
  unsigned int r = (u + 0x7FFFu + ((u >> 16) & 1u)) >> 16;
  return (unsigned short)r;
}
__device__ inline float bf2f(unsigned short s) {
  return __uint_as_float(((unsigned int)s) << 16);
}
__device__ inline void cvt8(const float* v, bfrag& hi, bfrag& lo) {
#pragma unroll
  for (int i = 0; i < 8; ++i) {
    unsigned short h = f2bf(v[i]);
    hi[i] = (short)h;
    lo[i] = (short)f2bf(v[i] - bf2f(h));
  }
}

// ---------------------------------------------------------------------------
// Prep: blocks 0..95 W_p frags, 96..102 W_q frags.
// frag layout per n-tile nt=c*6+w (4096 shorts = 8 KB each):
//   [ks(4)][hl(2)][lane(64)][j(8)] bf16
//   element = W_p[d][w*512 + c*32 + (lane&31)], d = ks*16 + (lane>>5)*8 + j
// ---------------------------------------------------------------------------
__global__ __launch_bounds__(256) void prep_kernel(
    const float* __restrict__ Wp, const float* __restrict__ Wq,
    unsigned short* __restrict__ fragWp, unsigned short* __restrict__ fragWq)
{
  const int b = blockIdx.x, t = threadIdx.x;
  if (b < 96) {
    __shared__ unsigned short lds[4096];
    const int c = b / 6, w = b - c * 6;
    const int colbase = w * 512 + c * 32;
    const int cl = t & 31, dg = t >> 5;
#pragma unroll
    for (int i = 0; i < 8; ++i) {
      const int d = dg * 8 + i;
      const float v = Wp[(size_t)d * 3072 + colbase + cl];
      const unsigned short hi = f2bf(v);
      const unsigned short lo = f2bf(v - bf2f(hi));
      const int ks = d >> 4;
      const int lane = ((d >> 3) & 1) * 32 + cl;
      const int j = d & 7;
      lds[(ks * 2 + 0) * 512 + lane * 8 + j] = hi;
      lds[(ks * 2 + 1) * 512 + lane * 8 + j] = lo;
    }
    __syncthreads();
    unsigned short* dst = fragWp + (size_t)b * 4096;
    ((uint4*)dst)[t] = ((const uint4*)lds)[t];
    ((uint4*)dst)[t + 256] = ((const uint4*)lds)[t + 256];
  } else {
    const int slot = b - 96;
    const int w = (slot == 6) ? 5 : slot;
    const float sgn = (slot == 6) ? -1.f : 1.f;
    for (int tt = t; tt < 512; tt += 256) {
      const int lane = tt >> 3, j = tt & 7;
      const int o = lane & 31, c = (lane >> 5) * 8 + j;
      const float v = sgn * Wq[(size_t)(w * 16 + c) * 32 + o];
      const unsigned short hi = f2bf(v);
      const unsigned short lo = f2bf(v - bf2f(hi));
      fragWq[slot * 1024 + lane * 8 + j] = hi;
      fragWq[slot * 1024 + 512 + lane * 8 + j] = lo;
    }
  }
}

// ---------------------------------------------------------------------------
// Main: 8 waves/block, 64 edges/block, grid 512. Wave = (pg = wv&1 edge-group
// of 32 edges) x (cr = wv>>1 c-residue mod 4). Each wave: 24 tiles (4 c's x 6
// w), direct global->VGPR A-frag stream (tile nt at nt*4096 shorts!), register
// ping-pong, zero K-loop barriers. z linear in c-partition: 4 partials per
// edge-group, LDS-reduced.
// ---------------------------------------------------------------------------
__global__ __launch_bounds__(512, 4) void main_kernel(
    const float* __restrict__ x_q, const float* __restrict__ x_k,
    const float* __restrict__ emb,
    const unsigned short* __restrict__ fragWp,
    const unsigned short* __restrict__ fragWq,
    float* __restrict__ z)
{
  __shared__ float xk_t[64][65];   // 16.6 KB, padded
  __shared__ float zred[8][32][4]; // 4 KB

  const int t = threadIdx.x;
  const int lane = t & 63, wv = t >> 6;
  const int pg = wv & 1, cr = wv >> 1;
  const int col = lane & 31, half = lane >> 5;
  const int eb = blockIdx.x * 64;
  const int el = pg * 32 + col;
  const int e = eb + el;

  // stage x_k transposed: 64 edges x 64 d; thread t -> edge t>>3, 8 d's
  {
    const int er = t >> 3, dq = (t & 7) * 8;
    const float* src = x_k + (size_t)(eb + er) * 64 + dq;
    float4 v0 = *(const float4*)(src);
    float4 v1 = *(const float4*)(src + 4);
    xk_t[dq + 0][er] = v0.x; xk_t[dq + 1][er] = v0.y;
    xk_t[dq + 2][er] = v0.z; xk_t[dq + 3][er] = v0.w;
    xk_t[dq + 4][er] = v1.x; xk_t[dq + 5][er] = v1.y;
    xk_t[dq + 6][er] = v1.z; xk_t[dq + 7][er] = v1.w;
  }

  // emb B-fragments hi/lo: B[k=d][col=edge], d = ks*16 + half*8 + j
  bfrag ebh[4], ebl[4];
#pragma unroll
  for (int ks = 0; ks < 4; ++ks) {
    float tmp[8];
    *(float4*)&tmp[0] = *(const float4*)(emb + (size_t)e * 64 + ks * 16 + half * 8);
    *(float4*)&tmp[4] = *(const float4*)(emb + (size_t)e * 64 + ks * 16 + half * 8 + 4);
    cvt8(tmp, ebh[ks], ebl[ks]);
  }

  facc ka0 = {0}, ka1 = {0}, ka2 = {0}, ka3 = {0};

  const unsigned short* fbase = fragWp + lane * 8;

  bfrag curh[4], curl[4], nxth[4], nxtl[4];
  {
    const unsigned short* gp = fbase + (size_t)(cr * 6) * 4096;  // idx 0: c=cr,w=0
#pragma unroll
    for (int ks = 0; ks < 4; ++ks) {
      *(uint4*)&curh[ks] = *(const uint4*)(gp + ks * 1024);
      *(uint4*)&curl[ks] = *(const uint4*)(gp + ks * 1024 + 512);
    }
  }

  __syncthreads();  // xk_t ready

  float xkc0 = 0.f, xkc1 = 0.f, xkc2 = 0.f, xkc3 = 0.f;

#pragma unroll 6
  for (int idx = 0; idx < 24; ++idx) {
    const int w = idx % 6;          // static under unroll-6
    // prefetch next tile (nidx): c = cr + 4*(nidx/6), w = nidx%6
    {
      const int nidx = (idx < 23) ? idx + 1 : 23;
      const int nc = cr + 4 * (nidx / 6);
      const int nw = nidx - 6 * (nidx / 6);
      const unsigned short* gp = fbase + (size_t)(nc * 6 + nw) * 4096;
#pragma unroll
      for (int ks = 0; ks < 4; ++ks) {
        *(uint4*)&nxth[ks] = *(const uint4*)(gp + ks * 1024);
        *(uint4*)&nxtl[ks] = *(const uint4*)(gp + ks * 1024 + 512);
      }
    }
    if (w == 0) {
      const int c = cr + 4 * (idx / 6);
      xkc0 = xk_t[c][el];
      xkc1 = xk_t[16 + c][el];
      xkc2 = xk_t[32 + c][el];
      xkc3 = xk_t[48 + c][el];
    }
    facc cc0 = {0.f}, cc1 = {0.f}, cc2 = {0.f};  // 3 independent chains of 4
#pragma unroll
    for (int ks = 0; ks < 4; ++ks) {
      cc0 = __builtin_amdgcn_mfma_f32_32x32x16_bf16(curh[ks], ebh[ks], cc0, 0, 0, 0);
      cc1 = __builtin_amdgcn_mfma_f32_32x32x16_bf16(curh[ks], ebl[ks], cc1, 0, 0, 0);
      cc2 = __builtin_amdgcn_mfma_f32_32x32x16_bf16(curl[ks], ebh[ks], cc2, 0, 0, 0);
    }
    // so2 contraction: w0:x0->m0 w1:x0->m2 w2:x2->m0 w3:x2->m2
    //                  w4:x1->m1,x3->m3   w5:x3->m1,-x1->m3
    if (w == 0) {
#pragma unroll
      for (int r = 0; r < 16; ++r) ka0[r] = fmaf(xkc0, cc0[r] + cc1[r] + cc2[r], ka0[r]);
    } else if (w == 1) {
#pragma unroll
      for (int r = 0; r < 16; ++r) ka2[r] = fmaf(xkc0, cc0[r] + cc1[r] + cc2[r], ka2[r]);
    } else if (w == 2) {
#pragma unroll
      for (int r = 0; r < 16; ++r) ka0[r] = fmaf(xkc2, cc0[r] + cc1[r] + cc2[r], ka0[r]);
    } else if (w == 3) {
#pragma unroll
      for (int r = 0; r < 16; ++r) ka2[r] = fmaf(xkc2, cc0[r] + cc1[r] + cc2[r], ka2[r]);
    } else if (w == 4) {
#pragma unroll
      for (int r = 0; r < 16; ++r) {
        const float s = cc0[r] + cc1[r] + cc2[r];
        ka1[r] = fmaf(xkc1, s, ka1[r]);
        ka3[r] = fmaf(xkc3, s, ka3[r]);
      }
    } else {
#pragma unroll
      for (int r = 0; r < 16; ++r) {
        const float s = cc0[r] + cc1[r] + cc2[r];
        ka1[r] = fmaf(xkc3, s, ka1[r]);
        ka3[r] = fmaf(-xkc1, s, ka3[r]);
      }
    }
#pragma unroll
    for (int ks = 0; ks < 4; ++ks) { curh[ks] = nxth[ks]; curl[ks] = nxtl[ks]; }
  }

  // ---- q via MFMA (same C layout as ka), partial z over this wave's c's
  bfrag xqh[4], xql[4];
#pragma unroll
  for (int a = 0; a < 4; ++a) {
    float tmp[8];
    *(float4*)&tmp[0] = *(const float4*)(x_q + (size_t)e * 64 + a * 16 + half * 8);
    *(float4*)&tmp[4] = *(const float4*)(x_q + (size_t)e * 64 + a * 16 + half * 8 + 4);
    cvt8(tmp, xqh[a], xql[a]);
  }
  float zp0 = 0.f, zp1 = 0.f, zp2 = 0.f, zp3 = 0.f;
  const int QA1[4] = {0, 1, 0, 3}, QS1[4] = {0, 4, 1, 4};
  const int QA2[4] = {2, 3, 2, 1}, QS2[4] = {2, 5, 3, 6};  // slot 6 = -Wq[5]
#pragma unroll
  for (int m = 0; m < 4; ++m) {
    facc qa = {0.f};
#pragma unroll
    for (int tm = 0; tm < 2; ++tm) {
      const int a = tm ? QA2[m] : QA1[m];
      const int sl = tm ? QS2[m] : QS1[m];
      bfrag wh, wl;
      *(uint4*)&wh = *(const uint4*)(fragWq + sl * 1024 + lane * 8);
      *(uint4*)&wl = *(const uint4*)(fragWq + sl * 1024 + 512 + lane * 8);
      qa = __builtin_amdgcn_mfma_f32_32x32x16_bf16(wh, xqh[a], qa, 0, 0, 0);
      qa = __builtin_amdgcn_mfma_f32_32x32x16_bf16(wh, xql[a], qa, 0, 0, 0);
      qa = __builtin_amdgcn_mfma_f32_32x32x16_bf16(wl, xqh[a], qa, 0, 0, 0);
    }
    const facc& km = (m == 0) ? ka0 : (m == 1) ? ka1 : (m == 2) ? ka2 : ka3;
#pragma unroll
    for (int r = 0; r < 16; ++r) {
      const float v = qa[r] * km[r];
      if (r < 4) zp0 += v;
      else if (r < 8) zp1 += v;
      else if (r < 12) zp2 += v;
      else zp3 += v;
    }
  }
  zp0 += __shfl_xor(zp0, 32);
  zp1 += __shfl_xor(zp1, 32);
  zp2 += __shfl_xor(zp2, 32);
  zp3 += __shfl_xor(zp3, 32);
  if (half == 0) {
    float4 v = {zp0, zp1, zp2, zp3};
    *(float4*)&zred[wv][col][0] = v;
  }
  __syncthreads();
  // reduce the 4 c-partials of this edge-group; waves cr==0 write out
  if (cr == 0 && half == 0) {
    float4 a = *(const float4*)&zred[pg][col][0];
    float4 b = *(const float4*)&zred[pg + 2][col][0];
    float4 c4 = *(const float4*)&zred[pg + 4][col][0];
    float4 d4 = *(const float4*)&zred[pg + 6][col][0];
    float4 o = {(a.x + b.x + c4.x + d4.x) * SCALE,
                (a.y + b.y + c4.y + d4.y) * SCALE,
                (a.z + b.z + c4.z + d4.z) * SCALE,
                (a.w + b.w + c4.w + d4.w) * SCALE};
    *(float4*)&z[(size_t)e * 4] = o;
  }
}

// ---------------------------------------------------------------------------
__global__ __launch_bounds__(256) void softmax_kernel(
    const float* __restrict__ z, const int* __restrict__ index,
    float* __restrict__ out)
{
  const int node = blockIdx.x * 4 + (threadIdx.x >> 6);
  const int lane = threadIdx.x & 63;
  int lo = 0, hi = E_TOTAL;
  while (lo < hi) { int mid = (lo + hi) >> 1; if (index[mid] < node) lo = mid + 1; else hi = mid; }
  const int start = lo;
  hi = E_TOTAL;
  while (lo < hi) { int mid = (lo + hi) >> 1; if (index[mid] < node + 1) lo = mid + 1; else hi = mid; }
  const int end = lo;
  if (start >= end) return;
  const int h = lane & 3, eo = lane >> 2;
  float m = -INFINITY;
  for (int e = start + eo; e < end; e += 16) m = fmaxf(m, z[(size_t)e * 4 + h]);
#pragma unroll
  for (int s = 4; s < 64; s <<= 1) m = fmaxf(m, __shfl_xor(m, s));
  float sum = 0.f;
  for (int e = start + eo; e < end; e += 16) sum += __expf(z[(size_t)e * 4 + h] - m);
#pragma unroll
  for (int s = 4; s < 64; s <<= 1) sum += __shfl_xor(sum, s);
  const float inv = 1.f / sum;
  for (int e = start + eo; e < end; e += 16)
    out[(size_t)e * 4 + h] = __expf(z[(size_t)e * 4 + h] - m) * inv;
}

extern "C" void kernel_launch(void* const* d_in, const int* in_sizes, int n_in,
                              void* d_out, int out_size, void* d_ws, size_t ws_size,
                              hipStream_t stream) {
  const float* x_q = (const float*)d_in[0];
  const float* x_k = (const float*)d_in[1];
  const float* emb = (const float*)d_in[2];
  const int* index = (const int*)d_in[3];
  const float* W_q = (const float*)d_in[4];
  const float* W_p = (const float*)d_in[5];
  float* out = (float*)d_out;

  char* ws = (char*)d_ws;
  float* z = (float*)ws;                                           // 524288 B
  unsigned short* fragWp = (unsigned short*)(ws + 524288);         // 786432 B
  unsigned short* fragWq = (unsigned short*)(ws + 524288 + 786432);// 14336 B

  prep_kernel<<<103, 256, 0, stream>>>(W_p, W_q, fragWp, fragWq);
  main_kernel<<<512, 512, 0, stream>>>(x_q, x_k, emb, fragWp, fragWq, z);
  softmax_kernel<<<1024, 256, 0, stream>>>(z, index, out);
}

// Round 7
// 425.473 us; speedup vs baseline: 1.0263x; 1.0263x over previous
//
#include <hip/hip_runtime.h>
#include <math.h>

#define E_TOTAL 32768
#define NUM_NODES 4096
#define SCALE 0.70710678118654752f

typedef __attribute__((ext_vector_type(8))) short bfrag;
typedef __attribute__((ext_vector_type(16))) float facc;

__device__ inline unsigned short f2bf(float f) {
  unsigned int u = __float_as_uint(f);
  unsigned int r = (u + 0x7FFFu + ((u >> 16) & 1u)) >> 16;
  return (unsigned short)r;
}
__device__ inline float bf2f(unsigned short s) {
  return __uint_as_float(((unsigned int)s) << 16);
}
__device__ inline void cvt8(const float* v, bfrag& hi, bfrag& lo) {
#pragma unroll
  for (int i = 0; i < 8; ++i) {
    unsigned short h = f2bf(v[i]);
    hi[i] = (short)h;
    lo[i] = (short)f2bf(v[i] - bf2f(h));
  }
}

// ---------------------------------------------------------------------------
// Prep: blocks 0..95 W_p frags, 96..102 W_q frags, 103..230 segment offsets.
// frag layout per n-tile nt=c*6+w (4096 shorts = 8 KB each):
//   [ks(4)][hl(2)][lane(64)][j(8)] bf16
//   element = W_p[d][w*512 + c*32 + (lane&31)], d = ks*16 + (lane>>5)*8 + j
// ---------------------------------------------------------------------------
__global__ __launch_bounds__(256) void prep_kernel(
    const float* __restrict__ Wp, const float* __restrict__ Wq,
    const int* __restrict__ index,
    unsigned short* __restrict__ fragWp, unsigned short* __restrict__ fragWq,
    int* __restrict__ offs)
{
  const int b = blockIdx.x, t = threadIdx.x;
  if (b < 96) {
    __shared__ unsigned short lds[4096];
    const int c = b / 6, w = b - c * 6;
    const int colbase = w * 512 + c * 32;
    const int cl = t & 31, dg = t >> 5;
#pragma unroll
    for (int i = 0; i < 8; ++i) {
      const int d = dg * 8 + i;
      const float v = Wp[(size_t)d * 3072 + colbase + cl];
      const unsigned short hi = f2bf(v);
      const unsigned short lo = f2bf(v - bf2f(hi));
      const int ks = d >> 4;
      const int lane = ((d >> 3) & 1) * 32 + cl;
      const int j = d & 7;
      lds[(ks * 2 + 0) * 512 + lane * 8 + j] = hi;
      lds[(ks * 2 + 1) * 512 + lane * 8 + j] = lo;
    }
    __syncthreads();
    unsigned short* dst = fragWp + (size_t)b * 4096;
    ((uint4*)dst)[t] = ((const uint4*)lds)[t];
    ((uint4*)dst)[t + 256] = ((const uint4*)lds)[t + 256];
  } else if (b < 103) {
    const int slot = b - 96;
    const int w = (slot == 6) ? 5 : slot;
    const float sgn = (slot == 6) ? -1.f : 1.f;
    for (int tt = t; tt < 512; tt += 256) {
      const int lane = tt >> 3, j = tt & 7;
      const int o = lane & 31, c = (lane >> 5) * 8 + j;
      const float v = sgn * Wq[(size_t)(w * 16 + c) * 32 + o];
      const unsigned short hi = f2bf(v);
      const unsigned short lo = f2bf(v - bf2f(hi));
      fragWq[slot * 1024 + lane * 8 + j] = hi;
      fragWq[slot * 1024 + 512 + lane * 8 + j] = lo;
    }
  } else {
    const int tg = (b - 103) * 256 + t;
    if (tg >= E_TOTAL) return;
    const int cur = index[tg];
    const int prev = (tg == 0) ? -1 : index[tg - 1];
    for (int n = prev + 1; n <= cur; ++n) offs[n] = tg;
    if (tg == E_TOTAL - 1)
      for (int n = cur + 1; n <= NUM_NODES; ++n) offs[n] = E_TOTAL;
  }
}

// ---------------------------------------------------------------------------
// Main: 4 waves/block (wave = c-residue cr mod 4), 32 edges/block, grid 1024.
// Each wave: 24 tiles (4 c's x 6 w), direct global->VGPR A-frag stream
// (tile nt at nt*4096 shorts), register ping-pong, zero K-loop barriers.
// All waves share the 32-edge group; z linear in c-partition: 4 partials
// reduced via LDS. __launch_bounds__(256,4): VGPR cap 128 (R3 body uses 116).
// ---------------------------------------------------------------------------
__global__ __launch_bounds__(256, 4) void main_kernel(
    const float* __restrict__ x_q, const float* __restrict__ x_k,
    const float* __restrict__ emb,
    const unsigned short* __restrict__ fragWp,
    const unsigned short* __restrict__ fragWq,
    float* __restrict__ z)
{
  __shared__ float xk_t[64][33];   // 8.4 KB, padded
  __shared__ float zred[4][32][4]; // 2 KB

  const int t = threadIdx.x;
  const int lane = t & 63, cr = t >> 6;
  const int col = lane & 31, half = lane >> 5;
  const int eb = blockIdx.x * 32;
  const int e = eb + col;

  // stage x_k transposed: 32 edges x 64 d; thread t -> edge t>>3, 8 d's
  {
    const int er = t >> 3, dq = (t & 7) * 8;
    const float* src = x_k + (size_t)(eb + er) * 64 + dq;
    float4 v0 = *(const float4*)(src);
    float4 v1 = *(const float4*)(src + 4);
    xk_t[dq + 0][er] = v0.x; xk_t[dq + 1][er] = v0.y;
    xk_t[dq + 2][er] = v0.z; xk_t[dq + 3][er] = v0.w;
    xk_t[dq + 4][er] = v1.x; xk_t[dq + 5][er] = v1.y;
    xk_t[dq + 6][er] = v1.z; xk_t[dq + 7][er] = v1.w;
  }

  // emb B-fragments hi/lo: B[k=d][col=edge], d = ks*16 + half*8 + j
  bfrag ebh[4], ebl[4];
#pragma unroll
  for (int ks = 0; ks < 4; ++ks) {
    float tmp[8];
    *(float4*)&tmp[0] = *(const float4*)(emb + (size_t)e * 64 + ks * 16 + half * 8);
    *(float4*)&tmp[4] = *(const float4*)(emb + (size_t)e * 64 + ks * 16 + half * 8 + 4);
    cvt8(tmp, ebh[ks], ebl[ks]);
  }

  facc ka0 = {0}, ka1 = {0}, ka2 = {0}, ka3 = {0};

  const unsigned short* fbase = fragWp + lane * 8;

  bfrag curh[4], curl[4], nxth[4], nxtl[4];
  {
    const unsigned short* gp = fbase + (size_t)(cr * 6) * 4096;  // idx 0: c=cr,w=0
#pragma unroll
    for (int ks = 0; ks < 4; ++ks) {
      *(uint4*)&curh[ks] = *(const uint4*)(gp + ks * 1024);
      *(uint4*)&curl[ks] = *(const uint4*)(gp + ks * 1024 + 512);
    }
  }

  __syncthreads();  // xk_t ready

  float xkc0 = 0.f, xkc1 = 0.f, xkc2 = 0.f, xkc3 = 0.f;

#pragma unroll 6
  for (int idx = 0; idx < 24; ++idx) {
    const int w = idx % 6;          // static under unroll-6
    // prefetch next tile (nidx): c = cr + 4*(nidx/6), w = nidx%6
    {
      const int nidx = (idx < 23) ? idx + 1 : 23;
      const int nc = cr + 4 * (nidx / 6);
      const int nw = nidx - 6 * (nidx / 6);
      const unsigned short* gp = fbase + (size_t)(nc * 6 + nw) * 4096;
#pragma unroll
      for (int ks = 0; ks < 4; ++ks) {
        *(uint4*)&nxth[ks] = *(const uint4*)(gp + ks * 1024);
        *(uint4*)&nxtl[ks] = *(const uint4*)(gp + ks * 1024 + 512);
      }
    }
    if (w == 0) {
      const int c = cr + 4 * (idx / 6);
      xkc0 = xk_t[c][col];
      xkc1 = xk_t[16 + c][col];
      xkc2 = xk_t[32 + c][col];
      xkc3 = xk_t[48 + c][col];
    }
    facc cc0 = {0.f}, cc1 = {0.f}, cc2 = {0.f};  // 3 independent chains of 4
#pragma unroll
    for (int ks = 0; ks < 4; ++ks) {
      cc0 = __builtin_amdgcn_mfma_f32_32x32x16_bf16(curh[ks], ebh[ks], cc0, 0, 0, 0);
      cc1 = __builtin_amdgcn_mfma_f32_32x32x16_bf16(curh[ks], ebl[ks], cc1, 0, 0, 0);
      cc2 = __builtin_amdgcn_mfma_f32_32x32x16_bf16(curl[ks], ebh[ks], cc2, 0, 0, 0);
    }
    // so2 contraction: w0:x0->m0 w1:x0->m2 w2:x2->m0 w3:x2->m2
    //                  w4:x1->m1,x3->m3   w5:x3->m1,-x1->m3
    if (w == 0) {
#pragma unroll
      for (int r = 0; r < 16; ++r) ka0[r] = fmaf(xkc0, cc0[r] + cc1[r] + cc2[r], ka0[r]);
    } else if (w == 1) {
#pragma unroll
      for (int r = 0; r < 16; ++r) ka2[r] = fmaf(xkc0, cc0[r] + cc1[r] + cc2[r], ka2[r]);
    } else if (w == 2) {
#pragma unroll
      for (int r = 0; r < 16; ++r) ka0[r] = fmaf(xkc2, cc0[r] + cc1[r] + cc2[r], ka0[r]);
    } else if (w == 3) {
#pragma unroll
      for (int r = 0; r < 16; ++r) ka2[r] = fmaf(xkc2, cc0[r] + cc1[r] + cc2[r], ka2[r]);
    } else if (w == 4) {
#pragma unroll
      for (int r = 0; r < 16; ++r) {
        const float s = cc0[r] + cc1[r] + cc2[r];
        ka1[r] = fmaf(xkc1, s, ka1[r]);
        ka3[r] = fmaf(xkc3, s, ka3[r]);
      }
    } else {
#pragma unroll
      for (int r = 0; r < 16; ++r) {
        const float s = cc0[r] + cc1[r] + cc2[r];
        ka1[r] = fmaf(xkc3, s, ka1[r]);
        ka3[r] = fmaf(-xkc1, s, ka3[r]);
      }
    }
#pragma unroll
    for (int ks = 0; ks < 4; ++ks) { curh[ks] = nxth[ks]; curl[ks] = nxtl[ks]; }
  }

  // ---- q via MFMA (same C layout as ka), partial z over this wave's c's
  bfrag xqh[4], xql[4];
#pragma unroll
  for (int a = 0; a < 4; ++a) {
    float tmp[8];
    *(float4*)&tmp[0] = *(const float4*)(x_q + (size_t)e * 64 + a * 16 + half * 8);
    *(float4*)&tmp[4] = *(const float4*)(x_q + (size_t)e * 64 + a * 16 + half * 8 + 4);
    cvt8(tmp, xqh[a], xql[a]);
  }
  float zp0 = 0.f, zp1 = 0.f, zp2 = 0.f, zp3 = 0.f;
  const int QA1[4] = {0, 1, 0, 3}, QS1[4] = {0, 4, 1, 4};
  const int QA2[4] = {2, 3, 2, 1}, QS2[4] = {2, 5, 3, 6};  // slot 6 = -Wq[5]
#pragma unroll
  for (int m = 0; m < 4; ++m) {
    facc qa = {0.f};
#pragma unroll
    for (int tm = 0; tm < 2; ++tm) {
      const int a = tm ? QA2[m] : QA1[m];
      const int sl = tm ? QS2[m] : QS1[m];
      bfrag wh, wl;
      *(uint4*)&wh = *(const uint4*)(fragWq + sl * 1024 + lane * 8);
      *(uint4*)&wl = *(const uint4*)(fragWq + sl * 1024 + 512 + lane * 8);
      qa = __builtin_amdgcn_mfma_f32_32x32x16_bf16(wh, xqh[a], qa, 0, 0, 0);
      qa = __builtin_amdgcn_mfma_f32_32x32x16_bf16(wh, xql[a], qa, 0, 0, 0);
      qa = __builtin_amdgcn_mfma_f32_32x32x16_bf16(wl, xqh[a], qa, 0, 0, 0);
    }
    const facc& km = (m == 0) ? ka0 : (m == 1) ? ka1 : (m == 2) ? ka2 : ka3;
#pragma unroll
    for (int r = 0; r < 16; ++r) {
      const float v = qa[r] * km[r];
      if (r < 4) zp0 += v;
      else if (r < 8) zp1 += v;
      else if (r < 12) zp2 += v;
      else zp3 += v;
    }
  }
  zp0 += __shfl_xor(zp0, 32);
  zp1 += __shfl_xor(zp1, 32);
  zp2 += __shfl_xor(zp2, 32);
  zp3 += __shfl_xor(zp3, 32);
  if (half == 0) {
    float4 v = {zp0, zp1, zp2, zp3};
    *(float4*)&zred[cr][col][0] = v;
  }
  __syncthreads();
  // reduce the 4 c-partials; wave 0 writes out
  if (cr == 0 && half == 0) {
    float4 a = *(const float4*)&zred[0][col][0];
    float4 b = *(const float4*)&zred[1][col][0];
    float4 c4 = *(const float4*)&zred[2][col][0];
    float4 d4 = *(const float4*)&zred[3][col][0];
    float4 o = {(a.x + b.x + c4.x + d4.x) * SCALE,
                (a.y + b.y + c4.y + d4.y) * SCALE,
                (a.z + b.z + c4.z + d4.z) * SCALE,
                (a.w + b.w + c4.w + d4.w) * SCALE};
    *(float4*)&z[(size_t)e * 4] = o;
  }
}

// ---------------------------------------------------------------------------
__global__ __launch_bounds__(256) void softmax_kernel(
    const float* __restrict__ z, const int* __restrict__ offs,
    float* __restrict__ out)
{
  const int node = blockIdx.x * 4 + (threadIdx.x >> 6);
  const int lane = threadIdx.x & 63;
  const int start = offs[node], end = offs[node + 1];
  if (start >= end) return;
  const int h = lane & 3, eo = lane >> 2;
  float m = -INFINITY;
  for (int e = start + eo; e < end; e += 16) m = fmaxf(m, z[(size_t)e * 4 + h]);
#pragma unroll
  for (int s = 4; s < 64; s <<= 1) m = fmaxf(m, __shfl_xor(m, s));
  float sum = 0.f;
  for (int e = start + eo; e < end; e += 16) sum += __expf(z[(size_t)e * 4 + h] - m);
#pragma unroll
  for (int s = 4; s < 64; s <<= 1) sum += __shfl_xor(sum, s);
  const float inv = 1.f / sum;
  for (int e = start + eo; e < end; e += 16)
    out[(size_t)e * 4 + h] = __expf(z[(size_t)e * 4 + h] - m) * inv;
}

extern "C" void kernel_launch(void* const* d_in, const int* in_sizes, int n_in,
                              void* d_out, int out_size, void* d_ws, size_t ws_size,
                              hipStream_t stream) {
  const float* x_q = (const float*)d_in[0];
  const float* x_k = (const float*)d_in[1];
  const float* emb = (const float*)d_in[2];
  const int* index = (const int*)d_in[3];
  const float* W_q = (const float*)d_in[4];
  const float* W_p = (const float*)d_in[5];
  float* out = (float*)d_out;

  char* ws = (char*)d_ws;
  float* z = (float*)ws;                                                     // 524288 B
  int* offs = (int*)(ws + 524288);                                           // 16388 B (pad 32 KB)
  unsigned short* fragWp = (unsigned short*)(ws + 524288 + 32768);           // 786432 B
  unsigned short* fragWq = (unsigned short*)(ws + 524288 + 32768 + 786432);  // 14336 B

  prep_kernel<<<231, 256, 0, stream>>>(W_p, W_q, index, fragWp, fragWq, offs);
  main_kernel<<<1024, 256, 0, stream>>>(x_q, x_k, emb, fragWp, fragWq, z);
  softmax_kernel<<<1024, 256, 0, stream>>>(z, offs, out);
}

// Round 8
// 126.046 us; speedup vs baseline: 3.4644x; 3.3755x over previous
//
#include <hip/hip_runtime.h>
#include <math.h>

#define E_TOTAL 32768
#define NUM_NODES 4096
#define SCALE 0.70710678118654752f

typedef __attribute__((ext_vector_type(8))) short bfrag;
typedef __attribute__((ext_vector_type(16))) float facc;

__device__ inline unsigned short f2bf(float f) {
  unsigned int u = __float_as_uint(f);
  unsigned int r = (u + 0x7FFFu + ((u >> 16) & 1u)) >> 16;
  return (unsigned short)r;
}
__device__ inline float bf2f(unsigned short s) {
  return __uint_as_float(((unsigned int)s) << 16);
}
__device__ inline void cvt8(const float* v, bfrag& hi, bfrag& lo) {
#pragma unroll
  for (int i = 0; i < 8; ++i) {
    unsigned short h = f2bf(v[i]);
    hi[i] = (short)h;
    lo[i] = (short)f2bf(v[i] - bf2f(h));
  }
}

// ---------------------------------------------------------------------------
// Prep: blocks 0..95 W_p frags, 96..102 W_q frags, 103..230 segment offsets.
// frag layout per n-tile nt=c*6+w (4096 shorts = 8 KB each):
//   [ks(4)][hl(2)][lane(64)][j(8)] bf16
//   element = W_p[d][w*512 + c*32 + (lane&31)], d = ks*16 + (lane>>5)*8 + j
// ---------------------------------------------------------------------------
__global__ __launch_bounds__(256) void prep_kernel(
    const float* __restrict__ Wp, const float* __restrict__ Wq,
    const int* __restrict__ index,
    unsigned short* __restrict__ fragWp, unsigned short* __restrict__ fragWq,
    int* __restrict__ offs)
{
  const int b = blockIdx.x, t = threadIdx.x;
  if (b < 96) {
    __shared__ unsigned short lds[4096];
    const int c = b / 6, w = b - c * 6;
    const int colbase = w * 512 + c * 32;
    const int cl = t & 31, dg = t >> 5;
#pragma unroll
    for (int i = 0; i < 8; ++i) {
      const int d = dg * 8 + i;
      const float v = Wp[(size_t)d * 3072 + colbase + cl];
      const unsigned short hi = f2bf(v);
      const unsigned short lo = f2bf(v - bf2f(hi));
      const int ks = d >> 4;
      const int lane = ((d >> 3) & 1) * 32 + cl;
      const int j = d & 7;
      lds[(ks * 2 + 0) * 512 + lane * 8 + j] = hi;
      lds[(ks * 2 + 1) * 512 + lane * 8 + j] = lo;
    }
    __syncthreads();
    unsigned short* dst = fragWp + (size_t)b * 4096;
    ((uint4*)dst)[t] = ((const uint4*)lds)[t];
    ((uint4*)dst)[t + 256] = ((const uint4*)lds)[t + 256];
  } else if (b < 103) {
    const int slot = b - 96;
    const int w = (slot == 6) ? 5 : slot;
    const float sgn = (slot == 6) ? -1.f : 1.f;
    for (int tt = t; tt < 512; tt += 256) {
      const int lane = tt >> 3, j = tt & 7;
      const int o = lane & 31, c = (lane >> 5) * 8 + j;
      const float v = sgn * Wq[(size_t)(w * 16 + c) * 32 + o];
      const unsigned short hi = f2bf(v);
      const unsigned short lo = f2bf(v - bf2f(hi));
      fragWq[slot * 1024 + lane * 8 + j] = hi;
      fragWq[slot * 1024 + 512 + lane * 8 + j] = lo;
    }
  } else {
    const int tg = (b - 103) * 256 + t;
    if (tg >= E_TOTAL) return;
    const int cur = index[tg];
    const int prev = (tg == 0) ? -1 : index[tg - 1];
    for (int n = prev + 1; n <= cur; ++n) offs[n] = tg;
    if (tg == E_TOTAL - 1)
      for (int n = cur + 1; n <= NUM_NODES; ++n) offs[n] = E_TOTAL;
  }
}

// ---------------------------------------------------------------------------
// Main: 4 waves/block, 32 edges/block (shared by all waves), grid 1024.
// Wave = (pr = wv&1 w-parity) x (ch = wv>>1 c-parity). Each wave: 24 tiles
// (3 w's x 8 c's), tile idx -> c = ch + 2*(idx/3), w = pr + 2*(idx%3).
// Direct global->VGPR A-frag stream (tile nt at nt*4096 shorts), register
// ping-pong, zero K-loop barriers. __launch_bounds__(256,2): no hard VGPR
// cap — R3's identical body compiled to 116 VGPR (4 waves/SIMD capable);
// forcing waves-per-eu=4 (R5/R6) caused catastrophic spill. z linear in the
// (pr,ch) partition: 4 partials per edge reduced via LDS.
// ---------------------------------------------------------------------------
__global__ __launch_bounds__(256, 2) void main_kernel(
    const float* __restrict__ x_q, const float* __restrict__ x_k,
    const float* __restrict__ emb,
    const unsigned short* __restrict__ fragWp,
    const unsigned short* __restrict__ fragWq,
    float* __restrict__ z)
{
  __shared__ float xk_t[64][33];   // 8.4 KB, padded
  __shared__ float zred[4][32][4]; // 2 KB

  const int t = threadIdx.x;
  const int lane = t & 63, wv = t >> 6;
  const int pr = wv & 1, ch = wv >> 1;
  const int col = lane & 31, half = lane >> 5;
  const int eb = blockIdx.x * 32;
  const int e = eb + col;

  // stage x_k transposed: 32 edges x 64 d; thread t -> edge t>>3, 8 d's
  {
    const int er = t >> 3, dq = (t & 7) * 8;
    const float* src = x_k + (size_t)(eb + er) * 64 + dq;
    float4 v0 = *(const float4*)(src);
    float4 v1 = *(const float4*)(src + 4);
    xk_t[dq + 0][er] = v0.x; xk_t[dq + 1][er] = v0.y;
    xk_t[dq + 2][er] = v0.z; xk_t[dq + 3][er] = v0.w;
    xk_t[dq + 4][er] = v1.x; xk_t[dq + 5][er] = v1.y;
    xk_t[dq + 6][er] = v1.z; xk_t[dq + 7][er] = v1.w;
  }

  // emb B-fragments hi/lo: B[k=d][col=edge], d = ks*16 + half*8 + j
  bfrag ebh[4], ebl[4];
#pragma unroll
  for (int ks = 0; ks < 4; ++ks) {
    float tmp[8];
    *(float4*)&tmp[0] = *(const float4*)(emb + (size_t)e * 64 + ks * 16 + half * 8);
    *(float4*)&tmp[4] = *(const float4*)(emb + (size_t)e * 64 + ks * 16 + half * 8 + 4);
    cvt8(tmp, ebh[ks], ebl[ks]);
  }

  facc ka0 = {0}, ka1 = {0}, ka2 = {0}, ka3 = {0};

  const unsigned short* fbase = fragWp + lane * 8;

  bfrag curh[4], curl[4], nxth[4], nxtl[4];
  {
    const unsigned short* gp = fbase + (size_t)(ch * 6 + pr) * 4096;  // idx 0
#pragma unroll
    for (int ks = 0; ks < 4; ++ks) {
      *(uint4*)&curh[ks] = *(const uint4*)(gp + ks * 1024);
      *(uint4*)&curl[ks] = *(const uint4*)(gp + ks * 1024 + 512);
    }
  }

  __syncthreads();  // xk_t ready

  float xkc0 = 0.f, xkc1 = 0.f, xkc2 = 0.f, xkc3 = 0.f;

#pragma unroll 6
  for (int idx = 0; idx < 24; ++idx) {
    const int j = idx % 3;          // static under unroll-6
    // prefetch next tile (nidx): c = ch + 2*(nidx/3), w = pr + 2*(nidx%3)
    {
      const int nidx = (idx < 23) ? idx + 1 : 23;
      const int nc = ch + 2 * (nidx / 3);
      const int nw = pr + 2 * (nidx - 3 * (nidx / 3));
      const unsigned short* gp = fbase + (size_t)(nc * 6 + nw) * 4096;
#pragma unroll
      for (int ks = 0; ks < 4; ++ks) {
        *(uint4*)&nxth[ks] = *(const uint4*)(gp + ks * 1024);
        *(uint4*)&nxtl[ks] = *(const uint4*)(gp + ks * 1024 + 512);
      }
    }
    if (j == 0) {
      const int c = ch + 2 * (idx / 3);
      xkc0 = xk_t[c][col];
      xkc1 = xk_t[16 + c][col];
      xkc2 = xk_t[32 + c][col];
      xkc3 = xk_t[48 + c][col];
    }
    facc cc0 = {0.f}, cc1 = {0.f}, cc2 = {0.f};  // 3 independent chains of 4
#pragma unroll
    for (int ks = 0; ks < 4; ++ks) {
      cc0 = __builtin_amdgcn_mfma_f32_32x32x16_bf16(curh[ks], ebh[ks], cc0, 0, 0, 0);
      cc1 = __builtin_amdgcn_mfma_f32_32x32x16_bf16(curh[ks], ebl[ks], cc1, 0, 0, 0);
      cc2 = __builtin_amdgcn_mfma_f32_32x32x16_bf16(curl[ks], ebh[ks], cc2, 0, 0, 0);
    }
    // so2: w0:x0->m0 w1:x0->m2 w2:x2->m0 w3:x2->m2 w4:x1->m1,x3->m3
    //      w5:x3->m1,-x1->m3.  This wave's w = pr + 2*j.
    if (j < 2) {
      const float xv = (j == 0) ? xkc0 : xkc2;
      if (pr == 0) {
#pragma unroll
        for (int r = 0; r < 16; ++r)
          ka0[r] = fmaf(xv, cc0[r] + cc1[r] + cc2[r], ka0[r]);
      } else {
#pragma unroll
        for (int r = 0; r < 16; ++r)
          ka2[r] = fmaf(xv, cc0[r] + cc1[r] + cc2[r], ka2[r]);
      }
    } else {
      if (pr == 0) {
#pragma unroll
        for (int r = 0; r < 16; ++r) {
          const float s = cc0[r] + cc1[r] + cc2[r];
          ka1[r] = fmaf(xkc1, s, ka1[r]);
          ka3[r] = fmaf(xkc3, s, ka3[r]);
        }
      } else {
#pragma unroll
        for (int r = 0; r < 16; ++r) {
          const float s = cc0[r] + cc1[r] + cc2[r];
          ka1[r] = fmaf(xkc3, s, ka1[r]);
          ka3[r] = fmaf(-xkc1, s, ka3[r]);
        }
      }
    }
#pragma unroll
    for (int ks = 0; ks < 4; ++ks) { curh[ks] = nxth[ks]; curl[ks] = nxtl[ks]; }
  }

  // ---- q via MFMA (same C layout as ka), partial z, 4-way LDS reduce
  bfrag xqh[4], xql[4];
#pragma unroll
  for (int a = 0; a < 4; ++a) {
    float tmp[8];
    *(float4*)&tmp[0] = *(const float4*)(x_q + (size_t)e * 64 + a * 16 + half * 8);
    *(float4*)&tmp[4] = *(const float4*)(x_q + (size_t)e * 64 + a * 16 + half * 8 + 4);
    cvt8(tmp, xqh[a], xql[a]);
  }
  float zp0 = 0.f, zp1 = 0.f, zp2 = 0.f, zp3 = 0.f;
  const int QA1[4] = {0, 1, 0, 3}, QS1[4] = {0, 4, 1, 4};
  const int QA2[4] = {2, 3, 2, 1}, QS2[4] = {2, 5, 3, 6};  // slot 6 = -Wq[5]
#pragma unroll
  for (int m = 0; m < 4; ++m) {
    facc qa = {0.f};
#pragma unroll
    for (int tm = 0; tm < 2; ++tm) {
      const int a = tm ? QA2[m] : QA1[m];
      const int sl = tm ? QS2[m] : QS1[m];
      bfrag wh, wl;
      *(uint4*)&wh = *(const uint4*)(fragWq + sl * 1024 + lane * 8);
      *(uint4*)&wl = *(const uint4*)(fragWq + sl * 1024 + 512 + lane * 8);
      qa = __builtin_amdgcn_mfma_f32_32x32x16_bf16(wh, xqh[a], qa, 0, 0, 0);
      qa = __builtin_amdgcn_mfma_f32_32x32x16_bf16(wh, xql[a], qa, 0, 0, 0);
      qa = __builtin_amdgcn_mfma_f32_32x32x16_bf16(wl, xqh[a], qa, 0, 0, 0);
    }
    const facc& km = (m == 0) ? ka0 : (m == 1) ? ka1 : (m == 2) ? ka2 : ka3;
#pragma unroll
    for (int r = 0; r < 16; ++r) {
      const float v = qa[r] * km[r];
      if (r < 4) zp0 += v;
      else if (r < 8) zp1 += v;
      else if (r < 12) zp2 += v;
      else zp3 += v;
    }
  }
  zp0 += __shfl_xor(zp0, 32);
  zp1 += __shfl_xor(zp1, 32);
  zp2 += __shfl_xor(zp2, 32);
  zp3 += __shfl_xor(zp3, 32);
  if (half == 0) {
    float4 v = {zp0, zp1, zp2, zp3};
    *(float4*)&zred[wv][col][0] = v;
  }
  __syncthreads();
  if (wv == 0 && half == 0) {
    float4 a = *(const float4*)&zred[0][col][0];
    float4 b = *(const float4*)&zred[1][col][0];
    float4 c4 = *(const float4*)&zred[2][col][0];
    float4 d4 = *(const float4*)&zred[3][col][0];
    float4 o = {(a.x + b.x + c4.x + d4.x) * SCALE,
                (a.y + b.y + c4.y + d4.y) * SCALE,
                (a.z + b.z + c4.z + d4.z) * SCALE,
                (a.w + b.w + c4.w + d4.w) * SCALE};
    *(float4*)&z[(size_t)e * 4] = o;
  }
}

// ---------------------------------------------------------------------------
__global__ __launch_bounds__(256) void softmax_kernel(
    const float* __restrict__ z, const int* __restrict__ offs,
    float* __restrict__ out)
{
  const int node = blockIdx.x * 4 + (threadIdx.x >> 6);
  const int lane = threadIdx.x & 63;
  const int start = offs[node], end = offs[node + 1];
  if (start >= end) return;
  const int h = lane & 3, eo = lane >> 2;
  float m = -INFINITY;
  for (int e = start + eo; e < end; e += 16) m = fmaxf(m, z[(size_t)e * 4 + h]);
#pragma unroll
  for (int s = 4; s < 64; s <<= 1) m = fmaxf(m, __shfl_xor(m, s));
  float sum = 0.f;
  for (int e = start + eo; e < end; e += 16) sum += __expf(z[(size_t)e * 4 + h] - m);
#pragma unroll
  for (int s = 4; s < 64; s <<= 1) sum += __shfl_xor(sum, s);
  const float inv = 1.f / sum;
  for (int e = start + eo; e < end; e += 16)
    out[(size_t)e * 4 + h] = __expf(z[(size_t)e * 4 + h] - m) * inv;
}

extern "C" void kernel_launch(void* const* d_in, const int* in_sizes, int n_in,
                              void* d_out, int out_size, void* d_ws, size_t ws_size,
                              hipStream_t stream) {
  const float* x_q = (const float*)d_in[0];
  const float* x_k = (const float*)d_in[1];
  const float* emb = (const float*)d_in[2];
  const int* index = (const int*)d_in[3];
  const float* W_q = (const float*)d_in[4];
  const float* W_p = (const float*)d_in[5];
  float* out = (float*)d_out;

  char* ws = (char*)d_ws;
  float* z = (float*)ws;                                                     // 524288 B
  int* offs = (int*)(ws + 524288);                                           // 16388 B (pad 32 KB)
  unsigned short* fragWp = (unsigned short*)(ws + 524288 + 32768);           // 786432 B
  unsigned short* fragWq = (unsigned short*)(ws + 524288 + 32768 + 786432);  // 14336 B

  prep_kernel<<<231, 256, 0, stream>>>(W_p, W_q, index, fragWp, fragWq, offs);
  main_kernel<<<1024, 256, 0, stream>>>(x_q, x_k, emb, fragWp, fragWq, z);
  softmax_kernel<<<1024, 256, 0, stream>>>(z, offs, out);
}